// Round 1
// baseline (298.206 us; speedup 1.0000x reference)
//
#include <hip/hip_runtime.h>

// YOLO decode + stable sort + greedy NMS, one block per batch item.
// S=7, B=2, C=20 -> 49 cells, 98 boxes, 1960 entries (box x class).

constexpr int S_  = 7;
constexpr int Cc  = 20;
constexpr int NCELL = 49;
constexpr int NBOX  = 98;     // 49*2
constexpr int NENT  = 1960;   // 98*20
constexpr int NPAD  = 2048;   // next pow2 for bitonic
constexpr int LPRED = 1470;   // 980 + 98 + 392
constexpr int BATCH = 16;
constexpr float IOU_THR_  = 0.1f;
constexpr float PROB_THR_ = 8e-25f;

__global__ __launch_bounds__(256)
void yolo_nms_kernel(const float* __restrict__ pred_all, float* __restrict__ out)
{
    const int b   = blockIdx.x;
    const int tid = threadIdx.x;
    const int bd  = blockDim.x;
    const float* pred = pred_all + b * LPRED;

    __shared__ float s_pred[LPRED];
    __shared__ float s_p[NPAD];
    __shared__ int   s_i[NPAD];
    __shared__ float bX[NBOX], bY[NBOX], bW[NBOX], bH[NBOX];
    __shared__ float bXh[NBOX], bXl[NBOX], bYh[NBOX], bYl[NBOX], bA[NBOX];
    __shared__ int   bCls[NBOX];
    __shared__ int   s_next;

    // ---- stage prediction in LDS ----
    for (int i = tid; i < LPRED; i += bd) s_pred[i] = pred[i];
    __syncthreads();

    // ---- decode the 98 boxes ----
    for (int bo = tid; bo < NBOX; bo += bd) {
        const int cell = bo >> 1;        // (i*7 + j)
        const int ci = cell / S_;        // i -> x offset
        const int cj = cell % S_;        // j -> y offset
        const float bx = s_pred[1078 + bo * 4 + 0];
        const float by = s_pred[1078 + bo * 4 + 1];
        const float bw = s_pred[1078 + bo * 4 + 2];
        const float bh = s_pred[1078 + bo * 4 + 3];
        // replicate reference float32 op order
        const float x = (bx + (float)ci) / 7.0f * 448.0f;
        const float y = (by + (float)cj) / 7.0f * 448.0f;
        const float w = bw * bw * 448.0f;
        const float h = bh * bh * 448.0f;
        bX[bo] = x; bY[bo] = y; bW[bo] = w; bH[bo] = h;
        bXh[bo] = x + 0.5f * w; bXl[bo] = x - 0.5f * w;
        bYh[bo] = y + 0.5f * h; bYl[bo] = y - 0.5f * h;
        bA[bo]  = w * h;
        // cls = argmax(mask) = first class with e_prob >= thr (0 if none)
        const float conf = s_pred[980 + bo];
        int cls = 0;
        for (int c = 0; c < Cc; ++c) {
            if (s_pred[cell * Cc + c] * conf >= PROB_THR_) { cls = c; break; }
        }
        bCls[bo] = cls;
    }

    // ---- fill (prob, idx) pairs, pad with sentinels ----
    for (int e = tid; e < NPAD; e += bd) {
        if (e < NENT) {
            const int bo   = e / Cc;
            const int c    = e - bo * Cc;
            const int cell = bo >> 1;
            const float ep = s_pred[cell * Cc + c] * s_pred[980 + bo];
            s_p[e] = (ep >= PROB_THR_) ? ep : 0.0f;
            s_i[e] = e;
        } else {
            s_p[e] = -1.0f;            // sorts after all real entries
            s_i[e] = 0x7FFFFFFF;
        }
    }
    __syncthreads();

    // ---- bitonic sort: order = (prob desc, idx asc) == stable argsort(-p) ----
    for (int k = 2; k <= NPAD; k <<= 1) {
        for (int js = k >> 1; js > 0; js >>= 1) {
            for (int idx = tid; idx < NPAD; idx += bd) {
                const int l = idx ^ js;
                if (l > idx) {
                    const float pa = s_p[idx], pb = s_p[l];
                    const int   ia = s_i[idx], ib = s_i[l];
                    const bool aFirst = (pa > pb) || (pa == pb && ia < ib);
                    const bool up = ((idx & k) == 0);
                    if (aFirst != up) {
                        s_p[idx] = pb; s_p[l] = pa;
                        s_i[idx] = ib; s_i[l] = ia;
                    }
                }
            }
            __syncthreads();
        }
    }

    // ---- greedy NMS over sorted order ----
    int cur = -1;
    while (true) {
        __syncthreads();
        if (tid == 0) s_next = NENT;
        __syncthreads();
        int lm = NENT;
        if (cur < 0) {
            // initial: find first positive-prob entry
            for (int j = tid; j < NENT; j += bd)
                if (s_p[j] > 0.0f) lm = min(lm, j);
        } else {
            const int pb = s_i[cur] / Cc;
            const float pXh = bXh[pb], pXl = bXl[pb];
            const float pYh = bYh[pb], pYl = bYl[pb];
            const float pA  = bA[pb];
            for (int j = cur + 1 + tid; j < NENT; j += bd) {
                const float p = s_p[j];
                if (p > 0.0f) {
                    const int jb = s_i[j] / Cc;
                    const float tb = fminf(pXh, bXh[jb]) - fmaxf(pXl, bXl[jb]);
                    const float lr = fminf(pYh, bYh[jb]) - fmaxf(pYl, bYl[jb]);
                    const float inter = (tb < 0.0f || lr < 0.0f) ? 0.0f : tb * lr;
                    const float iou = inter / (pA + bA[jb] - inter); // 0/0 -> NaN -> no suppress
                    if (iou > IOU_THR_) {
                        s_p[j] = 0.0f;
                    } else {
                        lm = min(lm, j);
                    }
                }
            }
        }
        atomicMin(&s_next, lm);
        __syncthreads();
        cur = s_next;
        if (cur >= NENT) break;
    }
    __syncthreads();

    // ---- write outputs: boxes (B,N,4) | probs (B,N) | cls (B,N) ----
    float* outBoxes = out + b * (NENT * 4);
    float* outProbs = out + BATCH * NENT * 4 + b * NENT;
    float* outCls   = out + BATCH * NENT * 5 + b * NENT;
    for (int k2 = tid; k2 < NENT; k2 += bd) {
        const int e  = s_i[k2];
        const int bo = e / Cc;
        float4 v = make_float4(bX[bo], bY[bo], bW[bo], bH[bo]);
        *reinterpret_cast<float4*>(outBoxes + k2 * 4) = v;
        outProbs[k2] = s_p[k2];
        outCls[k2]   = (float)bCls[bo];
    }
}

extern "C" void kernel_launch(void* const* d_in, const int* in_sizes, int n_in,
                              void* d_out, int out_size, void* d_ws, size_t ws_size,
                              hipStream_t stream)
{
    const float* pred = (const float*)d_in[0];
    float* out = (float*)d_out;
    yolo_nms_kernel<<<BATCH, 256, 0, stream>>>(pred, out);
}

// Round 2
// 34.200 us; speedup vs baseline: 8.7194x; 8.7194x over previous
//
#include <hip/hip_runtime.h>

// YOLO decode + stable sort + box-level greedy NMS. One block (1024 thr) per batch item.
// S=7, B=2, C=20 -> 49 cells, 98 boxes, 1960 entries.

constexpr int S_  = 7;
constexpr int Cc  = 20;
constexpr int NBOX  = 98;
constexpr int NENT  = 1960;
constexpr int NPAD  = 2048;
constexpr int LPRED = 1470;
constexpr int BATCH = 16;
constexpr float IOU_THR_  = 0.1f;
constexpr float PROB_THR_ = 8e-25f;

__global__ __launch_bounds__(1024)
void yolo_nms_kernel(const float* __restrict__ pred_all, float* __restrict__ out)
{
    const int b   = blockIdx.x;
    const int tid = threadIdx.x;
    const float* pred = pred_all + b * LPRED;

    __shared__ float s_pred[LPRED];
    __shared__ unsigned long long s_k[NPAD];          // (prob_bits<<32) | (0xFFFFFFFF - idx)
    __shared__ float bXh[NBOX], bXl[NBOX], bYh[NBOX], bYl[NBOX], bA[NBOX];
    __shared__ float4 bBox[NBOX];
    __shared__ unsigned int clsMask[NBOX];
    __shared__ unsigned long long iouRow[NBOX * 2];   // 128-bit suppression rows
    __shared__ int firstpos[NBOX];
    __shared__ int boxorder[NBOX];
    __shared__ int kept[NBOX];
    __shared__ int s_nvalid;

    // ---- stage prediction + init ----
    for (int i = tid; i < LPRED; i += 1024) s_pred[i] = pred[i];
    if (tid == 0) s_nvalid = 0;
    if (tid < NBOX) { clsMask[tid] = 0u; kept[tid] = 0; firstpos[tid] = 0x7FFFFFFF; }
    if (tid < 2 * NBOX) iouRow[tid] = 0ull;
    __syncthreads();

    // ---- decode 98 boxes (reference float32 op order) ----
    if (tid < NBOX) {
        const int bo = tid, cell = bo >> 1;
        const int ci = cell / S_, cj = cell % S_;
        const float bx = s_pred[1078 + bo * 4 + 0];
        const float by = s_pred[1078 + bo * 4 + 1];
        const float bw = s_pred[1078 + bo * 4 + 2];
        const float bh = s_pred[1078 + bo * 4 + 3];
        const float x = (bx + (float)ci) / 7.0f * 448.0f;
        const float y = (by + (float)cj) / 7.0f * 448.0f;
        const float w = bw * bw * 448.0f;
        const float h = bh * bh * 448.0f;
        bBox[bo] = make_float4(x, y, w, h);
        bXh[bo] = x + 0.5f * w;  bXl[bo] = x - 0.5f * w;
        bYh[bo] = y + 0.5f * h;  bYl[bo] = y - 0.5f * h;
        bA[bo]  = w * h;
    }
    __syncthreads();

    // ---- fill sort keys + per-box class mask ----
    for (int e = tid; e < NPAD; e += 1024) {
        unsigned long long key = 0ull;                // pads sort last
        if (e < NENT) {
            const int bo = e / Cc, c = e - bo * Cc, cell = bo >> 1;
            const float ep = s_pred[cell * Cc + c] * s_pred[980 + bo];
            if (ep >= PROB_THR_) {
                atomicOr(&clsMask[bo], 1u << c);
                key = ((unsigned long long)__float_as_uint(ep) << 32)
                    | (unsigned long long)(0xFFFFFFFFu - (unsigned)e);
            } else {
                key = (unsigned long long)(0xFFFFFFFFu - (unsigned)e); // prob 0, idx asc
            }
        }
        s_k[e] = key;
    }
    // ---- pairwise IoU suppression matrix (9604 pairs in parallel) ----
    for (int t = tid; t < NBOX * NBOX; t += 1024) {
        const int i = t / NBOX, j = t - i * NBOX;
        const float tb = fminf(bXh[i], bXh[j]) - fmaxf(bXl[i], bXl[j]);
        const float lr = fminf(bYh[i], bYh[j]) - fmaxf(bYl[i], bYl[j]);
        const float inter = (tb < 0.0f || lr < 0.0f) ? 0.0f : tb * lr;
        const float iou = inter / (bA[i] + bA[j] - inter);   // 0/0 -> NaN -> not > thr
        if (iou > IOU_THR_) atomicOr(&iouRow[i * 2 + (j >> 6)], 1ull << (j & 63));
    }
    __syncthreads();

    // ---- bitonic sort, descending by packed key (== stable argsort(-prob)) ----
    for (int k = 2; k <= NPAD; k <<= 1) {
        for (int js = k >> 1; js > 0; js >>= 1) {
            const int idx = ((tid & ~(js - 1)) << 1) | (tid & (js - 1));
            const int l   = idx | js;
            const unsigned long long a = s_k[idx], c = s_k[l];
            const bool dir = ((idx & k) == 0);       // descending blocks
            if ((a < c) == dir) { s_k[idx] = c; s_k[l] = a; }
            __syncthreads();
        }
    }

    // ---- first positive-prob sorted position per box ----
    for (int kp = tid; kp < NENT; kp += 1024) {
        const unsigned long long key = s_k[kp];
        if ((key >> 32) != 0ull) {
            const int idx = (int)(0xFFFFFFFFu - (unsigned)key);
            atomicMin(&firstpos[idx / Cc], kp);
        }
    }
    __syncthreads();

    // ---- rank boxes by firstpos (distinct positions -> permutation) ----
    if (tid < NBOX) {
        const int fp = firstpos[tid];
        if (fp != 0x7FFFFFFF) {
            int r = 0;
            for (int b2 = 0; b2 < NBOX; ++b2) r += (firstpos[b2] < fp) ? 1 : 0;
            boxorder[r] = tid;
            atomicAdd(&s_nvalid, 1);
        }
    }
    __syncthreads();

    // ---- serial greedy keep over <=98 boxes (register bitmask, rows prefetchable) ----
    if (tid == 0) {
        unsigned long long sup0 = 0ull, sup1 = 0ull;
        const int nv = s_nvalid;
        for (int r = 0; r < nv; ++r) {
            const int bb = boxorder[r];
            const unsigned long long r0 = iouRow[bb * 2];      // unconditional reads:
            const unsigned long long r1 = iouRow[bb * 2 + 1];  // lets compiler pipeline
            const bool supd = (bb < 64) ? ((sup0 >> bb) & 1ull)
                                        : ((sup1 >> (bb - 64)) & 1ull);
            if (!supd) { kept[bb] = 1; sup0 |= r0; sup1 |= r1; }
        }
    }
    __syncthreads();

    // ---- write outputs: boxes (B,N,4) | probs (B,N) | cls (B,N) ----
    float* outBoxes = out + b * (NENT * 4);
    float* outProbs = out + BATCH * NENT * 4 + b * NENT;
    float* outCls   = out + BATCH * NENT * 5 + b * NENT;
    for (int kp = tid; kp < NENT; kp += 1024) {
        const unsigned long long key = s_k[kp];
        const unsigned pb = (unsigned)(key >> 32);
        const int idx = (int)(0xFFFFFFFFu - (unsigned)key);
        const int bo  = idx / Cc;
        *reinterpret_cast<float4*>(outBoxes + kp * 4) = bBox[bo];
        outProbs[kp] = (pb != 0u && kp == firstpos[bo] && kept[bo])
                         ? __uint_as_float(pb) : 0.0f;
        const unsigned cm = clsMask[bo];
        outCls[kp] = (float)(cm ? (__ffs(cm) - 1) : 0);
    }
}

extern "C" void kernel_launch(void* const* d_in, const int* in_sizes, int n_in,
                              void* d_out, int out_size, void* d_ws, size_t ws_size,
                              hipStream_t stream)
{
    const float* pred = (const float*)d_in[0];
    float* out = (float*)d_out;
    yolo_nms_kernel<<<BATCH, 1024, 0, stream>>>(pred, out);
}